// Round 1
// baseline (1726.600 us; speedup 1.0000x reference)
//
#include <hip/hip_runtime.h>
#include <math.h>

// Decoder forward, MI355X gfx950. Round 0: correctness-first, bf16 MFMA GEMMs
// (m97 structure), MFMA flash attention, f32 residual stream.
//
// Dims (fixed): V=32000 D=1024 DEPTH=4 H=16 DH=64 FF=4096 B=1 N=2048

#define NSEQ 2048
#define DMODEL 1024
#define NH 16
#define DHEAD 64
#define FFD 4096
#define VOC 32000
#define NLAYER 4

typedef unsigned short u16;
typedef short bf16x8 __attribute__((ext_vector_type(8)));   // 8 bf16 in 4 VGPRs
typedef float f32x4 __attribute__((ext_vector_type(4)));

__device__ __forceinline__ u16 f2bf(float f) {
  unsigned int u = __builtin_bit_cast(unsigned int, f);
  u += 0x7fffu + ((u >> 16) & 1u);   // RNE
  return (u16)(u >> 16);
}

__device__ __forceinline__ void gload16(const void* g, void* l) {
  __builtin_amdgcn_global_load_lds((__attribute__((address_space(1))) void*)g,
                                   (__attribute__((address_space(3))) void*)l,
                                   16, 0, 0);
}

__device__ __forceinline__ f32x4 mfma16x32(bf16x8 a, bf16x8 b, f32x4 c) {
  return __builtin_amdgcn_mfma_f32_16x16x32_bf16(a, b, c, 0, 0, 0);
}

// ---------------------------------------------------------------- prep kernels

__global__ __launch_bounds__(256) void k_embed(const int* __restrict__ x,
                                               const float* __restrict__ emb,
                                               float* __restrict__ h) {
  const int n = blockIdx.x, t = threadIdx.x;
  const int tok = x[n];
  reinterpret_cast<float4*>(h + (size_t)n * DMODEL)[t] =
      reinterpret_cast<const float4*>(emb + (size_t)tok * DMODEL)[t];
}

__global__ void k_rope(float* __restrict__ ct, float* __restrict__ st) {
  const int n = blockIdx.x, p = threadIdx.x;  // 32 freq pairs
  const double inv = exp(-(double)(2 * p) / 64.0 * log(10000.0));
  const double a = (double)n * inv;
  ct[n * 32 + p] = (float)cos(a);
  st[n * 32 + p] = (float)sin(a);
}

// f32 [K][Nc]  ->  bf16 [Nc][K]   (weights into B^T layout for contiguous frags)
__global__ __launch_bounds__(256) void k_transpose(const float* __restrict__ in,
                                                   u16* __restrict__ out,
                                                   int K, int Nc) {
  __shared__ float tile[32][33];
  const int kb = blockIdx.x * 32, nb = blockIdx.y * 32;
  const int tx = threadIdx.x & 31, ty = threadIdx.x >> 5;
#pragma unroll
  for (int r = 0; r < 32; r += 8)
    tile[ty + r][tx] = in[(size_t)(kb + ty + r) * Nc + nb + tx];
  __syncthreads();
#pragma unroll
  for (int r = 0; r < 32; r += 8)
    out[(size_t)(nb + ty + r) * K + kb + tx] = f2bf(tile[tx][ty + r]);
}

// rms_norm(h)*gamma -> bf16 (GEMM A input). One row per block (256 thr, float4).
__global__ __launch_bounds__(256) void k_rmsnorm(const float* __restrict__ h,
                                                 const float* __restrict__ gamma,
                                                 u16* __restrict__ out) {
  __shared__ float red[4];
  const int n = blockIdx.x, t = threadIdx.x;
  const float4 v = reinterpret_cast<const float4*>(h + (size_t)n * DMODEL)[t];
  float ss = v.x * v.x + v.y * v.y + v.z * v.z + v.w * v.w;
#pragma unroll
  for (int off = 32; off; off >>= 1) ss += __shfl_down(ss, off);
  if ((t & 63) == 0) red[t >> 6] = ss;
  __syncthreads();
  const float tot = red[0] + red[1] + red[2] + red[3];
  const float inv = 32.0f / fmaxf(sqrtf(tot), 1e-12f);  // sqrt(1024)=32
  const float4 g = reinterpret_cast<const float4*>(gamma)[t];
  ushort4 o;
  o.x = f2bf(v.x * inv * g.x);
  o.y = f2bf(v.y * inv * g.y);
  o.z = f2bf(v.z * inv * g.z);
  o.w = f2bf(v.w * inv * g.w);
  reinterpret_cast<ushort4*>(out + (size_t)n * DMODEL)[t] = o;
}

// qkv f32 [N][3072] -> roped Q,K bf16 [H][N][64], V^T bf16 [H][64][N]
__global__ __launch_bounds__(256) void k_qkv_post(const float* __restrict__ qkv,
                                                  const float* __restrict__ ct,
                                                  const float* __restrict__ st,
                                                  u16* __restrict__ Qr,
                                                  u16* __restrict__ Kr,
                                                  u16* __restrict__ VT) {
  const int n = blockIdx.x;
  const int hh = blockIdx.y * 4 + (threadIdx.x >> 6);
  const int d = threadIdx.x & 63;  // == lane
  const float* base = qkv + (size_t)n * 3072 + hh * DHEAD + d;
  const float q = base[0], k = base[DMODEL], v = base[2 * DMODEL];
  const int p = d >> 1;
  const float c = ct[n * 32 + p], s = st[n * 32 + p];
  // rotate_half: even d -> -t[d+1], odd d -> t[d-1]; partner via lane xor 1
  const float qp = __shfl_xor(q, 1);
  const float kp = __shfl_xor(k, 1);
  const float sgn = (d & 1) ? 1.0f : -1.0f;
  Qr[((size_t)hh * NSEQ + n) * DHEAD + d] = f2bf(q * c + sgn * qp * s);
  Kr[((size_t)hh * NSEQ + n) * DHEAD + d] = f2bf(k * c + sgn * kp * s);
  VT[((size_t)hh * DHEAD + d) * NSEQ + n] = f2bf(v);
}

// ---------------------------------------------------------------- GEMM (m97-ish)
// C[M][Nc] = A_bf16[M][K] * BT_bf16[Nc][K]^T ; 128x128 tile, BK=32, 4 waves,
// global_load_lds(16B) staging, 16 mfma_16x16x32_bf16 per K-step.
// EPI: 0 store f32 | 1 +add store f32 | 2 +bias,gelu -> bf16 | 3 +bias+add f32

#define EPI_STORE 0
#define EPI_ADD 1
#define EPI_GELU 2
#define EPI_BIAS_ADD 3

template <int EPI>
__global__ __launch_bounds__(256) void k_gemm(const u16* __restrict__ A,
                                              const u16* __restrict__ BT,
                                              int K, int Nc,
                                              const float* __restrict__ bias,
                                              const float* __restrict__ add,
                                              float* __restrict__ outf,
                                              u16* __restrict__ outb) {
  __shared__ alignas(16) u16 Asm[128 * 32];
  __shared__ alignas(16) u16 Bsm[128 * 32];
  const int tid = threadIdx.x;
  const int m0 = blockIdx.x * 128, n0 = blockIdx.y * 128;
  const int w = tid >> 6, lane = tid & 63;
  const int wr = (w >> 1) * 64, wc = (w & 1) * 64;
  const int lr = lane & 15, lg = lane >> 4;

  f32x4 acc[4][4] = {};

  // staging map: thread tid covers tile bytes [tid*16, +16) and +4096 (rows +64)
  const int rowA = tid >> 2;
  const int colE = (tid & 3) * 8;
  const u16* Ag0 = A + (size_t)(m0 + rowA) * K + colE;
  const u16* Ag1 = A + (size_t)(m0 + rowA + 64) * K + colE;
  const u16* Bg0 = BT + (size_t)(n0 + rowA) * K + colE;
  const u16* Bg1 = BT + (size_t)(n0 + rowA + 64) * K + colE;
  char* lA = (char*)Asm + tid * 16;
  char* lB = (char*)Bsm + tid * 16;

  for (int kt = 0; kt < K; kt += 32) {
    __syncthreads();               // previous iter's reads done before overwrite
    gload16(Ag0 + kt, lA);
    gload16(Ag1 + kt, lA + 4096);
    gload16(Bg0 + kt, lB);
    gload16(Bg1 + kt, lB + 4096);
    __syncthreads();               // vmcnt(0) drain: tiles resident
    bf16x8 af[4], bfr[4];
#pragma unroll
    for (int i = 0; i < 4; ++i) {
      af[i] = *reinterpret_cast<const bf16x8*>(&Asm[(wr + i * 16 + lr) * 32 + lg * 8]);
      bfr[i] = *reinterpret_cast<const bf16x8*>(&Bsm[(wc + i * 16 + lr) * 32 + lg * 8]);
    }
#pragma unroll
    for (int mi = 0; mi < 4; ++mi)
#pragma unroll
      for (int ni = 0; ni < 4; ++ni)
        acc[mi][ni] = mfma16x32(af[mi], bfr[ni], acc[mi][ni]);
  }

#pragma unroll
  for (int mi = 0; mi < 4; ++mi) {
#pragma unroll
    for (int ni = 0; ni < 4; ++ni) {
      const int col = n0 + wc + ni * 16 + lr;
#pragma unroll
      for (int r = 0; r < 4; ++r) {
        const int row = m0 + wr + mi * 16 + lg * 4 + r;
        const size_t idx = (size_t)row * Nc + col;
        float v = acc[mi][ni][r];
        if (EPI == EPI_GELU) {
          v += bias[col];
          v = 0.5f * v * (1.0f + erff(v * 0.70710678118654752f));
          outb[idx] = f2bf(v);
        } else if (EPI == EPI_ADD) {
          outf[idx] = v + add[idx];
        } else if (EPI == EPI_BIAS_ADD) {
          outf[idx] = v + bias[col] + add[idx];
        } else {
          outf[idx] = v;
        }
      }
    }
  }
}

// ---------------------------------------------------------------- attention
// Flash, per (head, 64 q-rows) block; wave w owns rows q0=qb+16w..+15.
// S = Q K^T via mfma(Aq,Bk); online softmax f32; P -> per-wave LDS -> A-frag; PV
// uses V^T for contiguous B-frags. Output O/l as bf16 [N][1024].
__global__ __launch_bounds__(256) void k_attn(const u16* __restrict__ Qr,
                                              const u16* __restrict__ Kr,
                                              const u16* __restrict__ VT,
                                              u16* __restrict__ O) {
  __shared__ alignas(16) u16 Pl[4][16 * 32];  // per-wave P tile [16 rows][32 j]
  const int hh = blockIdx.y;
  const int w = threadIdx.x >> 6, lane = threadIdx.x & 63;
  const int lr = lane & 15, lg = lane >> 4;
  const int q0 = blockIdx.x * 64 + w * 16;
  const u16* Qh = Qr + (size_t)hh * NSEQ * DHEAD;
  const u16* Kh = Kr + (size_t)hh * NSEQ * DHEAD;
  const u16* Vh = VT + (size_t)hh * DHEAD * NSEQ;
  u16* Pw = Pl[w];

  const bf16x8 aq0 = *reinterpret_cast<const bf16x8*>(Qh + (q0 + lr) * DHEAD + lg * 8);
  const bf16x8 aq1 = *reinterpret_cast<const bf16x8*>(Qh + (q0 + lr) * DHEAD + 32 + lg * 8);

  f32x4 o0 = {}, o1 = {}, o2 = {}, o3 = {};
  float m[4], l[4];
#pragma unroll
  for (int r = 0; r < 4; ++r) { m[r] = -1e30f; l[r] = 0.0f; }

  const int jend = q0 + 15;  // last row this wave needs
  for (int j0 = 0; j0 <= jend; j0 += 32) {
    f32x4 s0 = {}, s1 = {};
    {
      bf16x8 bk;
      bk = *reinterpret_cast<const bf16x8*>(Kh + (j0 + lr) * DHEAD + lg * 8);
      s0 = mfma16x32(aq0, bk, s0);
      bk = *reinterpret_cast<const bf16x8*>(Kh + (j0 + lr) * DHEAD + 32 + lg * 8);
      s0 = mfma16x32(aq1, bk, s0);
      bk = *reinterpret_cast<const bf16x8*>(Kh + (j0 + 16 + lr) * DHEAD + lg * 8);
      s1 = mfma16x32(aq0, bk, s1);
      bk = *reinterpret_cast<const bf16x8*>(Kh + (j0 + 16 + lr) * DHEAD + 32 + lg * 8);
      s1 = mfma16x32(aq1, bk, s1);
    }
    float sv0[4], sv1[4], pm[4];
#pragma unroll
    for (int r = 0; r < 4; ++r) {
      const int irow = q0 + lg * 4 + r;
      sv0[r] = (j0 + lr > irow) ? -1e30f : s0[r] * 0.125f;
      sv1[r] = (j0 + 16 + lr > irow) ? -1e30f : s1[r] * 0.125f;
      pm[r] = fmaxf(sv0[r], sv1[r]);
    }
#pragma unroll
    for (int off = 1; off < 16; off <<= 1)
#pragma unroll
      for (int r = 0; r < 4; ++r) pm[r] = fmaxf(pm[r], __shfl_xor(pm[r], off));
    float p0[4], p1[4], rs[4];
    f32x4 fv;
#pragma unroll
    for (int r = 0; r < 4; ++r) {
      const float mn = fmaxf(m[r], pm[r]);
      fv[r] = __expf(m[r] - mn);
      m[r] = mn;
      p0[r] = __expf(sv0[r] - mn);
      p1[r] = __expf(sv1[r] - mn);
      rs[r] = p0[r] + p1[r];
    }
#pragma unroll
    for (int off = 1; off < 16; off <<= 1)
#pragma unroll
      for (int r = 0; r < 4; ++r) rs[r] += __shfl_xor(rs[r], off);
#pragma unroll
    for (int r = 0; r < 4; ++r) l[r] = l[r] * fv[r] + rs[r];
    o0 *= fv; o1 *= fv; o2 *= fv; o3 *= fv;

    // stage P (D-layout -> LDS row-major [16][32]), wave-private, no barrier
#pragma unroll
    for (int r = 0; r < 4; ++r) {
      Pw[(lg * 4 + r) * 32 + lr] = f2bf(p0[r]);
      Pw[(lg * 4 + r) * 32 + 16 + lr] = f2bf(p1[r]);
    }
    const bf16x8 pa = *reinterpret_cast<const bf16x8*>(Pw + lr * 32 + lg * 8);
    const u16* vb = Vh + j0 + lg * 8;
    o0 = mfma16x32(pa, *reinterpret_cast<const bf16x8*>(vb + (0 + lr) * NSEQ), o0);
    o1 = mfma16x32(pa, *reinterpret_cast<const bf16x8*>(vb + (16 + lr) * NSEQ), o1);
    o2 = mfma16x32(pa, *reinterpret_cast<const bf16x8*>(vb + (32 + lr) * NSEQ), o2);
    o3 = mfma16x32(pa, *reinterpret_cast<const bf16x8*>(vb + (48 + lr) * NSEQ), o3);
  }

#pragma unroll
  for (int r = 0; r < 4; ++r) {
    const int row = q0 + lg * 4 + r;
    const float invl = 1.0f / l[r];
    u16* orow = O + (size_t)row * DMODEL + hh * DHEAD;
    orow[0 * 16 + lr] = f2bf(o0[r] * invl);
    orow[1 * 16 + lr] = f2bf(o1[r] * invl);
    orow[2 * 16 + lr] = f2bf(o2[r] * invl);
    orow[3 * 16 + lr] = f2bf(o3[r] * invl);
  }
}

// ---------------------------------------------------------------- launch

extern "C" void kernel_launch(void* const* d_in, const int* in_sizes, int n_in,
                              void* d_out, int out_size, void* d_ws, size_t ws_size,
                              hipStream_t stream) {
  (void)in_sizes; (void)n_in;
  const int* x = (const int*)d_in[0];
  const float* emb = (const float*)d_in[1];
  const float* attn_gamma = (const float*)d_in[2];
  const float* w_qkv = (const float*)d_in[3];
  const float* w_attn_out = (const float*)d_in[4];
  const float* ff_gamma = (const float*)d_in[5];
  const float* w_ff1 = (const float*)d_in[6];
  const float* b_ff1 = (const float*)d_in[7];
  const float* w_ff2 = (const float*)d_in[8];
  const float* b_ff2 = (const float*)d_in[9];
  const float* final_gamma = (const float*)d_in[10];
  const float* w_logits = (const float*)d_in[11];
  float* out = (float*)d_out;

  // scratch: "early" group (dead before the logits GEMM) can live in d_out
  // (262 MB, only written at the very end) if ws is small; "final" group
  // (live during the logits GEMM) must be in ws.
  const size_t EARLY_NEED = 176ull << 20;
  const size_t FINAL_NEED = 72ull << 20;
  char* earlyBase;
  char* finalBase;
  if (ws_size >= EARLY_NEED + FINAL_NEED) {
    earlyBase = (char*)d_ws;
    finalBase = (char*)d_ws + EARLY_NEED;
  } else if (ws_size >= FINAL_NEED && (size_t)out_size * 4 >= EARLY_NEED) {
    earlyBase = (char*)d_out;
    finalBase = (char*)d_ws;
  } else {
    return;  // cannot run
  }
  size_t eoff = 0, foff = 0;
  auto ealloc = [&](size_t b) { void* p = earlyBase + eoff; eoff += (b + 255) & ~(size_t)255; return p; };
  auto falloc = [&](size_t b) { void* p = finalBase + foff; foff += (b + 255) & ~(size_t)255; return p; };

  u16* wqkvT = (u16*)ealloc((size_t)NLAYER * 3072 * DMODEL * 2);
  u16* wattnT = (u16*)ealloc((size_t)NLAYER * DMODEL * DMODEL * 2);
  u16* wff1T = (u16*)ealloc((size_t)NLAYER * FFD * DMODEL * 2);
  u16* wff2T = (u16*)ealloc((size_t)NLAYER * DMODEL * FFD * 2);
  float* h = (float*)ealloc((size_t)NSEQ * DMODEL * 4);
  float* qkv = (float*)ealloc((size_t)NSEQ * 3072 * 4);
  u16* Qr = (u16*)ealloc((size_t)NH * NSEQ * DHEAD * 2);
  u16* Kr = (u16*)ealloc((size_t)NH * NSEQ * DHEAD * 2);
  u16* VTb = (u16*)ealloc((size_t)NH * NSEQ * DHEAD * 2);
  u16* Ob = (u16*)ealloc((size_t)NSEQ * DMODEL * 2);
  u16* ff1b = (u16*)ealloc((size_t)NSEQ * FFD * 2);
  float* ct = (float*)ealloc((size_t)NSEQ * 32 * 4);
  float* st = (float*)ealloc((size_t)NSEQ * 32 * 4);
  u16* wlogT = (u16*)falloc((size_t)VOC * DMODEL * 2);
  u16* xn = (u16*)falloc((size_t)NSEQ * DMODEL * 2);

  k_rope<<<dim3(NSEQ), dim3(32), 0, stream>>>(ct, st);
  for (int lyr = 0; lyr < NLAYER; ++lyr) {
    k_transpose<<<dim3(32, 96), 256, 0, stream>>>(
        w_qkv + (size_t)lyr * DMODEL * 3072, wqkvT + (size_t)lyr * 3072 * DMODEL, DMODEL, 3072);
    k_transpose<<<dim3(32, 32), 256, 0, stream>>>(
        w_attn_out + (size_t)lyr * DMODEL * DMODEL, wattnT + (size_t)lyr * DMODEL * DMODEL, DMODEL, DMODEL);
    k_transpose<<<dim3(32, 128), 256, 0, stream>>>(
        w_ff1 + (size_t)lyr * DMODEL * FFD, wff1T + (size_t)lyr * FFD * DMODEL, DMODEL, FFD);
    k_transpose<<<dim3(128, 32), 256, 0, stream>>>(
        w_ff2 + (size_t)lyr * FFD * DMODEL, wff2T + (size_t)lyr * DMODEL * FFD, FFD, DMODEL);
  }
  k_transpose<<<dim3(32, 1000), 256, 0, stream>>>(w_logits, wlogT, DMODEL, VOC);

  k_embed<<<dim3(NSEQ), 256, 0, stream>>>(x, emb, h);

  for (int lyr = 0; lyr < NLAYER; ++lyr) {
    k_rmsnorm<<<dim3(NSEQ), 256, 0, stream>>>(h, attn_gamma + (size_t)lyr * DMODEL, xn);
    k_gemm<EPI_STORE><<<dim3(16, 24), 256, 0, stream>>>(
        xn, wqkvT + (size_t)lyr * 3072 * DMODEL, DMODEL, 3072, nullptr, nullptr, qkv, nullptr);
    k_qkv_post<<<dim3(NSEQ, NH / 4), 256, 0, stream>>>(qkv, ct, st, Qr, Kr, VTb);
    k_attn<<<dim3(NSEQ / 64, NH), 256, 0, stream>>>(Qr, Kr, VTb, Ob);
    k_gemm<EPI_ADD><<<dim3(16, 8), 256, 0, stream>>>(
        Ob, wattnT + (size_t)lyr * DMODEL * DMODEL, DMODEL, DMODEL, nullptr, h, h, nullptr);
    k_rmsnorm<<<dim3(NSEQ), 256, 0, stream>>>(h, ff_gamma + (size_t)lyr * DMODEL, xn);
    k_gemm<EPI_GELU><<<dim3(16, 32), 256, 0, stream>>>(
        xn, wff1T + (size_t)lyr * FFD * DMODEL, DMODEL, FFD, b_ff1 + (size_t)lyr * FFD, nullptr, nullptr, ff1b);
    k_gemm<EPI_BIAS_ADD><<<dim3(16, 8), 256, 0, stream>>>(
        ff1b, wff2T + (size_t)lyr * DMODEL * FFD, FFD, DMODEL, b_ff2 + (size_t)lyr * DMODEL, h, h, nullptr);
  }

  k_rmsnorm<<<dim3(NSEQ), 256, 0, stream>>>(h, final_gamma, xn);
  k_gemm<EPI_STORE><<<dim3(16, 250), 256, 0, stream>>>(
      xn, wlogT, DMODEL, VOC, nullptr, nullptr, out, nullptr);
}

// Round 2
// 1667.030 us; speedup vs baseline: 1.0357x; 1.0357x over previous
//
#include <hip/hip_runtime.h>
#include <math.h>

// Decoder forward, MI355X gfx950. Round 1: 8-phase counted-vmcnt GEMM
// (triple-buffered LDS) for K=1024 GEMMs; vectorized weight transpose.
//
// Dims (fixed): V=32000 D=1024 DEPTH=4 H=16 DH=64 FF=4096 B=1 N=2048

#define NSEQ 2048
#define DMODEL 1024
#define NH 16
#define DHEAD 64
#define FFD 4096
#define VOC 32000
#define NLAYER 4

typedef unsigned short u16;
typedef short bf16x8 __attribute__((ext_vector_type(8)));   // 8 bf16 in 4 VGPRs
typedef float f32x4 __attribute__((ext_vector_type(4)));

__device__ __forceinline__ u16 f2bf(float f) {
  unsigned int u = __builtin_bit_cast(unsigned int, f);
  u += 0x7fffu + ((u >> 16) & 1u);   // RNE
  return (u16)(u >> 16);
}

__device__ __forceinline__ void gload16(const void* g, void* l) {
  __builtin_amdgcn_global_load_lds((__attribute__((address_space(1))) void*)g,
                                   (__attribute__((address_space(3))) void*)l,
                                   16, 0, 0);
}

__device__ __forceinline__ f32x4 mfma16x32(bf16x8 a, bf16x8 b, f32x4 c) {
  return __builtin_amdgcn_mfma_f32_16x16x32_bf16(a, b, c, 0, 0, 0);
}

// ---------------------------------------------------------------- prep kernels

__global__ __launch_bounds__(256) void k_embed(const int* __restrict__ x,
                                               const float* __restrict__ emb,
                                               float* __restrict__ h) {
  const int n = blockIdx.x, t = threadIdx.x;
  const int tok = x[n];
  reinterpret_cast<float4*>(h + (size_t)n * DMODEL)[t] =
      reinterpret_cast<const float4*>(emb + (size_t)tok * DMODEL)[t];
}

__global__ void k_rope(float* __restrict__ ct, float* __restrict__ st) {
  const int n = blockIdx.x, p = threadIdx.x;  // 32 freq pairs
  const double inv = exp(-(double)(2 * p) / 64.0 * log(10000.0));
  const double a = (double)n * inv;
  ct[n * 32 + p] = (float)cos(a);
  st[n * 32 + p] = (float)sin(a);
}

// f32 [K][Nc] -> bf16 [Nc][K]; 64x64 tiles, float4 reads, ushort4 writes.
__global__ __launch_bounds__(256) void k_transpose(const float* __restrict__ in,
                                                   u16* __restrict__ out,
                                                   int K, int Nc) {
  __shared__ float tile[64][65];
  const int kb = blockIdx.x * 64, nb = blockIdx.y * 64;
  const int tr = threadIdx.x >> 4;       // 0..15
  const int tc = threadIdx.x & 15;       // 0..15
#pragma unroll
  for (int r = 0; r < 64; r += 16) {
    const float4 v = *reinterpret_cast<const float4*>(
        &in[(size_t)(kb + r + tr) * Nc + nb + tc * 4]);
    tile[r + tr][tc * 4 + 0] = v.x;
    tile[r + tr][tc * 4 + 1] = v.y;
    tile[r + tr][tc * 4 + 2] = v.z;
    tile[r + tr][tc * 4 + 3] = v.w;
  }
  __syncthreads();
#pragma unroll
  for (int r = 0; r < 64; r += 16) {
    const int n = r + tr;
    ushort4 o;
    o.x = f2bf(tile[tc * 4 + 0][n]);
    o.y = f2bf(tile[tc * 4 + 1][n]);
    o.z = f2bf(tile[tc * 4 + 2][n]);
    o.w = f2bf(tile[tc * 4 + 3][n]);
    *reinterpret_cast<ushort4*>(&out[(size_t)(nb + n) * K + kb + tc * 4]) = o;
  }
}

// rms_norm(h)*gamma -> bf16 (GEMM A input). One row per block (256 thr, float4).
__global__ __launch_bounds__(256) void k_rmsnorm(const float* __restrict__ h,
                                                 const float* __restrict__ gamma,
                                                 u16* __restrict__ out) {
  __shared__ float red[4];
  const int n = blockIdx.x, t = threadIdx.x;
  const float4 v = reinterpret_cast<const float4*>(h + (size_t)n * DMODEL)[t];
  float ss = v.x * v.x + v.y * v.y + v.z * v.z + v.w * v.w;
#pragma unroll
  for (int off = 32; off; off >>= 1) ss += __shfl_down(ss, off);
  if ((t & 63) == 0) red[t >> 6] = ss;
  __syncthreads();
  const float tot = red[0] + red[1] + red[2] + red[3];
  const float inv = 32.0f / fmaxf(sqrtf(tot), 1e-12f);  // sqrt(1024)=32
  const float4 g = reinterpret_cast<const float4*>(gamma)[t];
  ushort4 o;
  o.x = f2bf(v.x * inv * g.x);
  o.y = f2bf(v.y * inv * g.y);
  o.z = f2bf(v.z * inv * g.z);
  o.w = f2bf(v.w * inv * g.w);
  reinterpret_cast<ushort4*>(out + (size_t)n * DMODEL)[t] = o;
}

// qkv f32 [N][3072] -> roped Q,K bf16 [H][N][64], V^T bf16 [H][64][N]
__global__ __launch_bounds__(256) void k_qkv_post(const float* __restrict__ qkv,
                                                  const float* __restrict__ ct,
                                                  const float* __restrict__ st,
                                                  u16* __restrict__ Qr,
                                                  u16* __restrict__ Kr,
                                                  u16* __restrict__ VT) {
  const int n = blockIdx.x;
  const int hh = blockIdx.y * 4 + (threadIdx.x >> 6);
  const int d = threadIdx.x & 63;  // == lane
  const float* base = qkv + (size_t)n * 3072 + hh * DHEAD + d;
  const float q = base[0], k = base[DMODEL], v = base[2 * DMODEL];
  const int p = d >> 1;
  const float c = ct[n * 32 + p], s = st[n * 32 + p];
  const float qp = __shfl_xor(q, 1);
  const float kp = __shfl_xor(k, 1);
  const float sgn = (d & 1) ? 1.0f : -1.0f;
  Qr[((size_t)hh * NSEQ + n) * DHEAD + d] = f2bf(q * c + sgn * qp * s);
  Kr[((size_t)hh * NSEQ + n) * DHEAD + d] = f2bf(k * c + sgn * kp * s);
  VT[((size_t)hh * DHEAD + d) * NSEQ + n] = f2bf(v);
}

// ---------------------------------------------------------------- GEMM epilogues
#define EPI_STORE 0
#define EPI_ADD 1
#define EPI_GELU 2
#define EPI_BIAS_ADD 3

// ---------------- 128x128 m97-structure GEMM (kept for N=1024 shapes) ----------
template <int EPI>
__global__ __launch_bounds__(256) void k_gemm(const u16* __restrict__ A,
                                              const u16* __restrict__ BT,
                                              int K, int Nc,
                                              const float* __restrict__ bias,
                                              const float* __restrict__ add,
                                              float* __restrict__ outf,
                                              u16* __restrict__ outb) {
  __shared__ alignas(16) u16 Asm[128 * 32];
  __shared__ alignas(16) u16 Bsm[128 * 32];
  const int tid = threadIdx.x;
  const int m0 = blockIdx.x * 128, n0 = blockIdx.y * 128;
  const int w = tid >> 6, lane = tid & 63;
  const int wr = (w >> 1) * 64, wc = (w & 1) * 64;
  const int lr = lane & 15, lg = lane >> 4;

  f32x4 acc[4][4] = {};

  const int rowA = tid >> 2;
  const int colE = (tid & 3) * 8;
  const u16* Ag0 = A + (size_t)(m0 + rowA) * K + colE;
  const u16* Ag1 = A + (size_t)(m0 + rowA + 64) * K + colE;
  const u16* Bg0 = BT + (size_t)(n0 + rowA) * K + colE;
  const u16* Bg1 = BT + (size_t)(n0 + rowA + 64) * K + colE;
  char* lA = (char*)Asm + tid * 16;
  char* lB = (char*)Bsm + tid * 16;

  for (int kt = 0; kt < K; kt += 32) {
    __syncthreads();
    gload16(Ag0 + kt, lA);
    gload16(Ag1 + kt, lA + 4096);
    gload16(Bg0 + kt, lB);
    gload16(Bg1 + kt, lB + 4096);
    __syncthreads();
    bf16x8 af[4], bfr[4];
#pragma unroll
    for (int i = 0; i < 4; ++i) {
      af[i] = *reinterpret_cast<const bf16x8*>(&Asm[(wr + i * 16 + lr) * 32 + lg * 8]);
      bfr[i] = *reinterpret_cast<const bf16x8*>(&Bsm[(wc + i * 16 + lr) * 32 + lg * 8]);
    }
#pragma unroll
    for (int mi = 0; mi < 4; ++mi)
#pragma unroll
      for (int ni = 0; ni < 4; ++ni)
        acc[mi][ni] = mfma16x32(af[mi], bfr[ni], acc[mi][ni]);
  }

#pragma unroll
  for (int mi = 0; mi < 4; ++mi) {
#pragma unroll
    for (int ni = 0; ni < 4; ++ni) {
      const int col = n0 + wc + ni * 16 + lr;
#pragma unroll
      for (int r = 0; r < 4; ++r) {
        const int row = m0 + wr + mi * 16 + lg * 4 + r;
        const size_t idx = (size_t)row * Nc + col;
        float v = acc[mi][ni][r];
        if (EPI == EPI_GELU) {
          v += bias[col];
          v = 0.5f * v * (1.0f + erff(v * 0.70710678118654752f));
          outb[idx] = f2bf(v);
        } else if (EPI == EPI_ADD) {
          outf[idx] = v + add[idx];
        } else if (EPI == EPI_BIAS_ADD) {
          outf[idx] = v + bias[col] + add[idx];
        } else {
          outf[idx] = v;
        }
      }
    }
  }
}

// ---------------- 8-phase counted-vmcnt GEMM, 128x256xBK64, triple-buffer -----
// Invariant: tile t is read from buf[t%3]; tile t+2 is staged into buf[(t+2)%3]
// (never the buffer being read). Boundary wait vmcnt(6) retires exactly tile
// t+1's 6 loads while tile t+2's 6 stay in flight (counted, never drain-0).
// 8 waves (2x4), wave tile 64x64, 4 phases/tile, 8 MFMA/phase, setprio on MFMA.

#define GP_ABYTES (128 * 64 * 2)                  // 16 KB
#define GP_BBYTES (256 * 64 * 2)                  // 32 KB
#define GP_BUFB (GP_ABYTES + GP_BBYTES)           // 48 KB/buffer, x3 = 144 KB

template <int EPI>
__global__ __launch_bounds__(512, 2) void k_gemm8p(const u16* __restrict__ A,
                                                   const u16* __restrict__ BT,
                                                   int K, int Nc, int NB,
                                                   const float* __restrict__ bias,
                                                   float* __restrict__ outf,
                                                   u16* __restrict__ outb) {
  __shared__ alignas(16) char sm[3 * GP_BUFB];
  const int nt = K >> 6;

  // XCD-aware swizzle (grids here are all %8==0), n-fastest for A-panel L2 reuse
  const int nwg = gridDim.x;
  const int bid = blockIdx.x;
  int swz = bid;
  if ((nwg & 7) == 0) swz = (bid & 7) * (nwg >> 3) + (bid >> 3);
  const int mb = swz / NB, nb = swz % NB;
  const int m0 = mb * 128, n0 = nb * 256;

  const int tid = threadIdx.x;
  const int w = tid >> 6, lane = tid & 63;
  const int wr = w >> 2, wc = w & 3;  // 2 x 4 wave grid
  const int lr = lane & 15, lg = lane >> 4;

  // staging: thread covers 16B chunks; per tile: 2 A-loads + 4 B-loads
  const int srow = tid >> 3;            // 0..63
  const int scol = (tid & 7) * 8;       // k elems
  const u16* ga0 = A + (size_t)(m0 + srow) * K + scol;
  const u16* ga1 = A + (size_t)(m0 + 64 + srow) * K + scol;
  const u16* gb0 = BT + (size_t)(n0 + srow) * K + scol;
  const u16* gb1 = BT + (size_t)(n0 + 64 + srow) * K + scol;
  const u16* gb2 = BT + (size_t)(n0 + 128 + srow) * K + scol;
  const u16* gb3 = BT + (size_t)(n0 + 192 + srow) * K + scol;
  const int ldOff = srow * 128 + (tid & 7) * 16;   // within region (row=128B)

#define GP_STAGE_A(b)                                   \
  {                                                     \
    gload16(ga0, sm + (b)*GP_BUFB + ldOff);             \
    gload16(ga1, sm + (b)*GP_BUFB + ldOff + 8192);      \
  }
#define GP_STAGE_B01(b)                                         \
  {                                                             \
    gload16(gb0, sm + (b)*GP_BUFB + GP_ABYTES + ldOff);         \
    gload16(gb1, sm + (b)*GP_BUFB + GP_ABYTES + ldOff + 8192);  \
  }
#define GP_STAGE_B23(b)                                          \
  {                                                              \
    gload16(gb2, sm + (b)*GP_BUFB + GP_ABYTES + ldOff + 16384);  \
    gload16(gb3, sm + (b)*GP_BUFB + GP_ABYTES + ldOff + 24576);  \
  }
#define GP_ADV() \
  { ga0 += 64; ga1 += 64; gb0 += 64; gb1 += 64; gb2 += 64; gb3 += 64; }

  // prologue: stage tiles 0,1; wait tile0 (6 of tile1's stay in flight)
  GP_STAGE_A(0) GP_STAGE_B01(0) GP_STAGE_B23(0) GP_ADV();
  GP_STAGE_A(1) GP_STAGE_B01(1) GP_STAGE_B23(1) GP_ADV();
  asm volatile("s_waitcnt vmcnt(6)" ::: "memory");
  __builtin_amdgcn_s_barrier();

  f32x4 acc[4][4] = {};
  int cur = 0, nx2 = 2;
  for (int t = 0; t < nt; ++t) {
    const u16* Ab = (const u16*)(sm + cur * GP_BUFB);
    const u16* Bb = (const u16*)(sm + cur * GP_BUFB + GP_ABYTES);
    const bool pf = (t + 2 < nt);
    bf16x8 bf[4][2];
#pragma unroll
    for (int p = 0; p < 4; ++p) {
      // ds-load this phase's A frags (mi = p), and all B frags at p==0
      bf16x8 af0 = *reinterpret_cast<const bf16x8*>(
          Ab + (wr * 64 + p * 16 + lr) * 64 + lg * 8);
      bf16x8 af1 = *reinterpret_cast<const bf16x8*>(
          Ab + (wr * 64 + p * 16 + lr) * 64 + 32 + lg * 8);
      if (p == 0) {
#pragma unroll
        for (int nj = 0; nj < 4; ++nj) {
#pragma unroll
          for (int ks = 0; ks < 2; ++ks)
            bf[nj][ks] = *reinterpret_cast<const bf16x8*>(
                Bb + (wc * 64 + nj * 16 + lr) * 64 + ks * 32 + lg * 8);
        }
      }
      // stage tile t+2's share for this phase
      if (pf) {
        if (p == 0) GP_STAGE_A(nx2)
        else if (p == 1) GP_STAGE_B01(nx2)
        else if (p == 2) GP_STAGE_B23(nx2)
      }
      __builtin_amdgcn_s_barrier();
      __builtin_amdgcn_s_setprio(1);
#pragma unroll
      for (int nj = 0; nj < 4; ++nj) {
        acc[p][nj] = mfma16x32(af0, bf[nj][0], acc[p][nj]);
        acc[p][nj] = mfma16x32(af1, bf[nj][1], acc[p][nj]);
      }
      __builtin_amdgcn_s_setprio(0);
    }
    if (pf) GP_ADV();
    if (t + 1 < nt) {
      __builtin_amdgcn_sched_barrier(0);
      if (pf) asm volatile("s_waitcnt vmcnt(6)" ::: "memory");
      else    asm volatile("s_waitcnt vmcnt(0)" ::: "memory");
      __builtin_amdgcn_s_barrier();
      __builtin_amdgcn_sched_barrier(0);
    }
    cur = (cur == 2) ? 0 : cur + 1;
    nx2 = (nx2 == 2) ? 0 : nx2 + 1;
  }

#pragma unroll
  for (int mi = 0; mi < 4; ++mi) {
#pragma unroll
    for (int nj = 0; nj < 4; ++nj) {
      const int col = n0 + wc * 64 + nj * 16 + lr;
#pragma unroll
      for (int r = 0; r < 4; ++r) {
        const int row = m0 + wr * 64 + mi * 16 + lg * 4 + r;
        float v = acc[mi][nj][r];
        if (EPI == EPI_GELU) {
          v += bias[col];
          v = 0.5f * v * (1.0f + erff(v * 0.70710678118654752f));
          outb[(size_t)row * Nc + col] = f2bf(v);
        } else {
          outf[(size_t)row * Nc + col] = v;
        }
      }
    }
  }
#undef GP_STAGE_A
#undef GP_STAGE_B01
#undef GP_STAGE_B23
#undef GP_ADV
}

// ---------------------------------------------------------------- attention
__global__ __launch_bounds__(256) void k_attn(const u16* __restrict__ Qr,
                                              const u16* __restrict__ Kr,
                                              const u16* __restrict__ VT,
                                              u16* __restrict__ O) {
  __shared__ alignas(16) u16 Pl[4][16 * 32];
  const int hh = blockIdx.y;
  const int w = threadIdx.x >> 6, lane = threadIdx.x & 63;
  const int lr = lane & 15, lg = lane >> 4;
  const int q0 = blockIdx.x * 64 + w * 16;
  const u16* Qh = Qr + (size_t)hh * NSEQ * DHEAD;
  const u16* Kh = Kr + (size_t)hh * NSEQ * DHEAD;
  const u16* Vh = VT + (size_t)hh * DHEAD * NSEQ;
  u16* Pw = Pl[w];

  const bf16x8 aq0 = *reinterpret_cast<const bf16x8*>(Qh + (q0 + lr) * DHEAD + lg * 8);
  const bf16x8 aq1 = *reinterpret_cast<const bf16x8*>(Qh + (q0 + lr) * DHEAD + 32 + lg * 8);

  f32x4 o0 = {}, o1 = {}, o2 = {}, o3 = {};
  float m[4], l[4];
#pragma unroll
  for (int r = 0; r < 4; ++r) { m[r] = -1e30f; l[r] = 0.0f; }

  const int jend = q0 + 15;
  for (int j0 = 0; j0 <= jend; j0 += 32) {
    f32x4 s0 = {}, s1 = {};
    {
      bf16x8 bk;
      bk = *reinterpret_cast<const bf16x8*>(Kh + (j0 + lr) * DHEAD + lg * 8);
      s0 = mfma16x32(aq0, bk, s0);
      bk = *reinterpret_cast<const bf16x8*>(Kh + (j0 + lr) * DHEAD + 32 + lg * 8);
      s0 = mfma16x32(aq1, bk, s0);
      bk = *reinterpret_cast<const bf16x8*>(Kh + (j0 + 16 + lr) * DHEAD + lg * 8);
      s1 = mfma16x32(aq0, bk, s1);
      bk = *reinterpret_cast<const bf16x8*>(Kh + (j0 + 16 + lr) * DHEAD + 32 + lg * 8);
      s1 = mfma16x32(aq1, bk, s1);
    }
    float sv0[4], sv1[4], pm[4];
#pragma unroll
    for (int r = 0; r < 4; ++r) {
      const int irow = q0 + lg * 4 + r;
      sv0[r] = (j0 + lr > irow) ? -1e30f : s0[r] * 0.125f;
      sv1[r] = (j0 + 16 + lr > irow) ? -1e30f : s1[r] * 0.125f;
      pm[r] = fmaxf(sv0[r], sv1[r]);
    }
#pragma unroll
    for (int off = 1; off < 16; off <<= 1)
#pragma unroll
      for (int r = 0; r < 4; ++r) pm[r] = fmaxf(pm[r], __shfl_xor(pm[r], off));
    float p0[4], p1[4], rs[4];
    f32x4 fv;
#pragma unroll
    for (int r = 0; r < 4; ++r) {
      const float mn = fmaxf(m[r], pm[r]);
      fv[r] = __expf(m[r] - mn);
      m[r] = mn;
      p0[r] = __expf(sv0[r] - mn);
      p1[r] = __expf(sv1[r] - mn);
      rs[r] = p0[r] + p1[r];
    }
#pragma unroll
    for (int off = 1; off < 16; off <<= 1)
#pragma unroll
      for (int r = 0; r < 4; ++r) rs[r] += __shfl_xor(rs[r], off);
#pragma unroll
    for (int r = 0; r < 4; ++r) l[r] = l[r] * fv[r] + rs[r];
    o0 *= fv; o1 *= fv; o2 *= fv; o3 *= fv;

#pragma unroll
    for (int r = 0; r < 4; ++r) {
      Pw[(lg * 4 + r) * 32 + lr] = f2bf(p0[r]);
      Pw[(lg * 4 + r) * 32 + 16 + lr] = f2bf(p1[r]);
    }
    const bf16x8 pa = *reinterpret_cast<const bf16x8*>(Pw + lr * 32 + lg * 8);
    const u16* vb = Vh + j0 + lg * 8;
    o0 = mfma16x32(pa, *reinterpret_cast<const bf16x8*>(vb + (0 + lr) * NSEQ), o0);
    o1 = mfma16x32(pa, *reinterpret_cast<const bf16x8*>(vb + (16 + lr) * NSEQ), o1);
    o2 = mfma16x32(pa, *reinterpret_cast<const bf16x8*>(vb + (32 + lr) * NSEQ), o2);
    o3 = mfma16x32(pa, *reinterpret_cast<const bf16x8*>(vb + (48 + lr) * NSEQ), o3);
  }

#pragma unroll
  for (int r = 0; r < 4; ++r) {
    const int row = q0 + lg * 4 + r;
    const float invl = 1.0f / l[r];
    u16* orow = O + (size_t)row * DMODEL + hh * DHEAD;
    orow[0 * 16 + lr] = f2bf(o0[r] * invl);
    orow[1 * 16 + lr] = f2bf(o1[r] * invl);
    orow[2 * 16 + lr] = f2bf(o2[r] * invl);
    orow[3 * 16 + lr] = f2bf(o3[r] * invl);
  }
}

// ---------------------------------------------------------------- launch

extern "C" void kernel_launch(void* const* d_in, const int* in_sizes, int n_in,
                              void* d_out, int out_size, void* d_ws, size_t ws_size,
                              hipStream_t stream) {
  (void)in_sizes; (void)n_in;
  const int* x = (const int*)d_in[0];
  const float* emb = (const float*)d_in[1];
  const float* attn_gamma = (const float*)d_in[2];
  const float* w_qkv = (const float*)d_in[3];
  const float* w_attn_out = (const float*)d_in[4];
  const float* ff_gamma = (const float*)d_in[5];
  const float* w_ff1 = (const float*)d_in[6];
  const float* b_ff1 = (const float*)d_in[7];
  const float* w_ff2 = (const float*)d_in[8];
  const float* b_ff2 = (const float*)d_in[9];
  const float* final_gamma = (const float*)d_in[10];
  const float* w_logits = (const float*)d_in[11];
  float* out = (float*)d_out;

  const size_t EARLY_NEED = 176ull << 20;
  const size_t FINAL_NEED = 72ull << 20;
  char* earlyBase;
  char* finalBase;
  if (ws_size >= EARLY_NEED + FINAL_NEED) {
    earlyBase = (char*)d_ws;
    finalBase = (char*)d_ws + EARLY_NEED;
  } else if (ws_size >= FINAL_NEED && (size_t)out_size * 4 >= EARLY_NEED) {
    earlyBase = (char*)d_out;
    finalBase = (char*)d_ws;
  } else {
    return;
  }
  size_t eoff = 0, foff = 0;
  auto ealloc = [&](size_t b) { void* p = earlyBase + eoff; eoff += (b + 255) & ~(size_t)255; return p; };
  auto falloc = [&](size_t b) { void* p = finalBase + foff; foff += (b + 255) & ~(size_t)255; return p; };

  u16* wqkvT = (u16*)ealloc((size_t)NLAYER * 3072 * DMODEL * 2);
  u16* wattnT = (u16*)ealloc((size_t)NLAYER * DMODEL * DMODEL * 2);
  u16* wff1T = (u16*)ealloc((size_t)NLAYER * FFD * DMODEL * 2);
  u16* wff2T = (u16*)ealloc((size_t)NLAYER * DMODEL * FFD * 2);
  float* h = (float*)ealloc((size_t)NSEQ * DMODEL * 4);
  float* qkv = (float*)ealloc((size_t)NSEQ * 3072 * 4);
  u16* Qr = (u16*)ealloc((size_t)NH * NSEQ * DHEAD * 2);
  u16* Kr = (u16*)ealloc((size_t)NH * NSEQ * DHEAD * 2);
  u16* VTb = (u16*)ealloc((size_t)NH * NSEQ * DHEAD * 2);
  u16* Ob = (u16*)ealloc((size_t)NSEQ * DMODEL * 2);
  u16* ff1b = (u16*)ealloc((size_t)NSEQ * FFD * 2);
  float* ct = (float*)ealloc((size_t)NSEQ * 32 * 4);
  float* st = (float*)ealloc((size_t)NSEQ * 32 * 4);
  u16* wlogT = (u16*)falloc((size_t)VOC * DMODEL * 2);
  u16* xn = (u16*)falloc((size_t)NSEQ * DMODEL * 2);

  k_rope<<<dim3(NSEQ), dim3(32), 0, stream>>>(ct, st);
  for (int lyr = 0; lyr < NLAYER; ++lyr) {
    k_transpose<<<dim3(16, 48), 256, 0, stream>>>(
        w_qkv + (size_t)lyr * DMODEL * 3072, wqkvT + (size_t)lyr * 3072 * DMODEL, DMODEL, 3072);
    k_transpose<<<dim3(16, 16), 256, 0, stream>>>(
        w_attn_out + (size_t)lyr * DMODEL * DMODEL, wattnT + (size_t)lyr * DMODEL * DMODEL, DMODEL, DMODEL);
    k_transpose<<<dim3(16, 64), 256, 0, stream>>>(
        w_ff1 + (size_t)lyr * DMODEL * FFD, wff1T + (size_t)lyr * FFD * DMODEL, DMODEL, FFD);
    k_transpose<<<dim3(64, 16), 256, 0, stream>>>(
        w_ff2 + (size_t)lyr * FFD * DMODEL, wff2T + (size_t)lyr * DMODEL * FFD, FFD, DMODEL);
  }
  k_transpose<<<dim3(16, 500), 256, 0, stream>>>(w_logits, wlogT, DMODEL, VOC);

  k_embed<<<dim3(NSEQ), 256, 0, stream>>>(x, emb, h);

  for (int lyr = 0; lyr < NLAYER; ++lyr) {
    k_rmsnorm<<<dim3(NSEQ), 256, 0, stream>>>(h, attn_gamma + (size_t)lyr * DMODEL, xn);
    k_gemm8p<EPI_STORE><<<dim3(16 * 12), 512, 0, stream>>>(
        xn, wqkvT + (size_t)lyr * 3072 * DMODEL, DMODEL, 3072, 12, nullptr, qkv, nullptr);
    k_qkv_post<<<dim3(NSEQ, NH / 4), 256, 0, stream>>>(qkv, ct, st, Qr, Kr, VTb);
    k_attn<<<dim3(NSEQ / 64, NH), 256, 0, stream>>>(Qr, Kr, VTb, Ob);
    k_gemm<EPI_ADD><<<dim3(16, 8), 256, 0, stream>>>(
        Ob, wattnT + (size_t)lyr * DMODEL * DMODEL, DMODEL, DMODEL, nullptr, h, h, nullptr);
    k_rmsnorm<<<dim3(NSEQ), 256, 0, stream>>>(h, ff_gamma + (size_t)lyr * DMODEL, xn);
    k_gemm8p<EPI_GELU><<<dim3(16 * 16), 512, 0, stream>>>(
        xn, wff1T + (size_t)lyr * FFD * DMODEL, DMODEL, FFD, 16, b_ff1 + (size_t)lyr * FFD, nullptr, ff1b);
    k_gemm<EPI_BIAS_ADD><<<dim3(16, 8), 256, 0, stream>>>(
        ff1b, wff2T + (size_t)lyr * DMODEL * FFD, FFD, DMODEL, b_ff2 + (size_t)lyr * DMODEL, h, h, nullptr);
  }

  k_rmsnorm<<<dim3(NSEQ), 256, 0, stream>>>(h, final_gamma, xn);
  k_gemm8p<EPI_STORE><<<dim3(16 * 125), 512, 0, stream>>>(
      xn, wlogT, DMODEL, VOC, 125, nullptr, out, nullptr);
}

// Round 3
// 1619.124 us; speedup vs baseline: 1.0664x; 1.0296x over previous
//
#include <hip/hip_runtime.h>
#include <math.h>

// Decoder forward, MI355X gfx950. Round 2: k_gemm8p gets (a) T2 st_16x32 LDS
// swizzle (pre-swizzled global_load_lds source + swizzled ds_read, rule #21),
// (b) m-fast block ordering inside XCD chunks for B-panel L2 residency.
//
// Dims (fixed): V=32000 D=1024 DEPTH=4 H=16 DH=64 FF=4096 B=1 N=2048

#define NSEQ 2048
#define DMODEL 1024
#define NH 16
#define DHEAD 64
#define FFD 4096
#define VOC 32000
#define NLAYER 4

typedef unsigned short u16;
typedef short bf16x8 __attribute__((ext_vector_type(8)));   // 8 bf16 in 4 VGPRs
typedef float f32x4 __attribute__((ext_vector_type(4)));

__device__ __forceinline__ u16 f2bf(float f) {
  unsigned int u = __builtin_bit_cast(unsigned int, f);
  u += 0x7fffu + ((u >> 16) & 1u);   // RNE
  return (u16)(u >> 16);
}

__device__ __forceinline__ void gload16(const void* g, void* l) {
  __builtin_amdgcn_global_load_lds((__attribute__((address_space(1))) void*)g,
                                   (__attribute__((address_space(3))) void*)l,
                                   16, 0, 0);
}

__device__ __forceinline__ f32x4 mfma16x32(bf16x8 a, bf16x8 b, f32x4 c) {
  return __builtin_amdgcn_mfma_f32_16x16x32_bf16(a, b, c, 0, 0, 0);
}

// ---------------------------------------------------------------- prep kernels

__global__ __launch_bounds__(256) void k_embed(const int* __restrict__ x,
                                               const float* __restrict__ emb,
                                               float* __restrict__ h) {
  const int n = blockIdx.x, t = threadIdx.x;
  const int tok = x[n];
  reinterpret_cast<float4*>(h + (size_t)n * DMODEL)[t] =
      reinterpret_cast<const float4*>(emb + (size_t)tok * DMODEL)[t];
}

__global__ void k_rope(float* __restrict__ ct, float* __restrict__ st) {
  const int n = blockIdx.x, p = threadIdx.x;  // 32 freq pairs
  const double inv = exp(-(double)(2 * p) / 64.0 * log(10000.0));
  const double a = (double)n * inv;
  ct[n * 32 + p] = (float)cos(a);
  st[n * 32 + p] = (float)sin(a);
}

// f32 [K][Nc] -> bf16 [Nc][K]; 64x64 tiles, float4 reads, ushort4 writes.
__global__ __launch_bounds__(256) void k_transpose(const float* __restrict__ in,
                                                   u16* __restrict__ out,
                                                   int K, int Nc) {
  __shared__ float tile[64][65];
  const int kb = blockIdx.x * 64, nb = blockIdx.y * 64;
  const int tr = threadIdx.x >> 4;       // 0..15
  const int tc = threadIdx.x & 15;       // 0..15
#pragma unroll
  for (int r = 0; r < 64; r += 16) {
    const float4 v = *reinterpret_cast<const float4*>(
        &in[(size_t)(kb + r + tr) * Nc + nb + tc * 4]);
    tile[r + tr][tc * 4 + 0] = v.x;
    tile[r + tr][tc * 4 + 1] = v.y;
    tile[r + tr][tc * 4 + 2] = v.z;
    tile[r + tr][tc * 4 + 3] = v.w;
  }
  __syncthreads();
#pragma unroll
  for (int r = 0; r < 64; r += 16) {
    const int n = r + tr;
    ushort4 o;
    o.x = f2bf(tile[tc * 4 + 0][n]);
    o.y = f2bf(tile[tc * 4 + 1][n]);
    o.z = f2bf(tile[tc * 4 + 2][n]);
    o.w = f2bf(tile[tc * 4 + 3][n]);
    *reinterpret_cast<ushort4*>(&out[(size_t)(nb + n) * K + kb + tc * 4]) = o;
  }
}

// rms_norm(h)*gamma -> bf16 (GEMM A input). One row per block (256 thr, float4).
__global__ __launch_bounds__(256) void k_rmsnorm(const float* __restrict__ h,
                                                 const float* __restrict__ gamma,
                                                 u16* __restrict__ out) {
  __shared__ float red[4];
  const int n = blockIdx.x, t = threadIdx.x;
  const float4 v = reinterpret_cast<const float4*>(h + (size_t)n * DMODEL)[t];
  float ss = v.x * v.x + v.y * v.y + v.z * v.z + v.w * v.w;
#pragma unroll
  for (int off = 32; off; off >>= 1) ss += __shfl_down(ss, off);
  if ((t & 63) == 0) red[t >> 6] = ss;
  __syncthreads();
  const float tot = red[0] + red[1] + red[2] + red[3];
  const float inv = 32.0f / fmaxf(sqrtf(tot), 1e-12f);  // sqrt(1024)=32
  const float4 g = reinterpret_cast<const float4*>(gamma)[t];
  ushort4 o;
  o.x = f2bf(v.x * inv * g.x);
  o.y = f2bf(v.y * inv * g.y);
  o.z = f2bf(v.z * inv * g.z);
  o.w = f2bf(v.w * inv * g.w);
  reinterpret_cast<ushort4*>(out + (size_t)n * DMODEL)[t] = o;
}

// qkv f32 [N][3072] -> roped Q,K bf16 [H][N][64], V^T bf16 [H][64][N]
__global__ __launch_bounds__(256) void k_qkv_post(const float* __restrict__ qkv,
                                                  const float* __restrict__ ct,
                                                  const float* __restrict__ st,
                                                  u16* __restrict__ Qr,
                                                  u16* __restrict__ Kr,
                                                  u16* __restrict__ VT) {
  const int n = blockIdx.x;
  const int hh = blockIdx.y * 4 + (threadIdx.x >> 6);
  const int d = threadIdx.x & 63;  // == lane
  const float* base = qkv + (size_t)n * 3072 + hh * DHEAD + d;
  const float q = base[0], k = base[DMODEL], v = base[2 * DMODEL];
  const int p = d >> 1;
  const float c = ct[n * 32 + p], s = st[n * 32 + p];
  const float qp = __shfl_xor(q, 1);
  const float kp = __shfl_xor(k, 1);
  const float sgn = (d & 1) ? 1.0f : -1.0f;
  Qr[((size_t)hh * NSEQ + n) * DHEAD + d] = f2bf(q * c + sgn * qp * s);
  Kr[((size_t)hh * NSEQ + n) * DHEAD + d] = f2bf(k * c + sgn * kp * s);
  VT[((size_t)hh * DHEAD + d) * NSEQ + n] = f2bf(v);
}

// ---------------------------------------------------------------- GEMM epilogues
#define EPI_STORE 0
#define EPI_ADD 1
#define EPI_GELU 2
#define EPI_BIAS_ADD 3

// ---------------- 128x128 m97-structure GEMM (kept for N=1024 shapes) ----------
template <int EPI>
__global__ __launch_bounds__(256) void k_gemm(const u16* __restrict__ A,
                                              const u16* __restrict__ BT,
                                              int K, int Nc,
                                              const float* __restrict__ bias,
                                              const float* __restrict__ add,
                                              float* __restrict__ outf,
                                              u16* __restrict__ outb) {
  __shared__ alignas(16) u16 Asm[128 * 32];
  __shared__ alignas(16) u16 Bsm[128 * 32];
  const int tid = threadIdx.x;
  const int m0 = blockIdx.x * 128, n0 = blockIdx.y * 128;
  const int w = tid >> 6, lane = tid & 63;
  const int wr = (w >> 1) * 64, wc = (w & 1) * 64;
  const int lr = lane & 15, lg = lane >> 4;

  f32x4 acc[4][4] = {};

  const int rowA = tid >> 2;
  const int colE = (tid & 3) * 8;
  const u16* Ag0 = A + (size_t)(m0 + rowA) * K + colE;
  const u16* Ag1 = A + (size_t)(m0 + rowA + 64) * K + colE;
  const u16* Bg0 = BT + (size_t)(n0 + rowA) * K + colE;
  const u16* Bg1 = BT + (size_t)(n0 + rowA + 64) * K + colE;
  char* lA = (char*)Asm + tid * 16;
  char* lB = (char*)Bsm + tid * 16;

  for (int kt = 0; kt < K; kt += 32) {
    __syncthreads();
    gload16(Ag0 + kt, lA);
    gload16(Ag1 + kt, lA + 4096);
    gload16(Bg0 + kt, lB);
    gload16(Bg1 + kt, lB + 4096);
    __syncthreads();
    bf16x8 af[4], bfr[4];
#pragma unroll
    for (int i = 0; i < 4; ++i) {
      af[i] = *reinterpret_cast<const bf16x8*>(&Asm[(wr + i * 16 + lr) * 32 + lg * 8]);
      bfr[i] = *reinterpret_cast<const bf16x8*>(&Bsm[(wc + i * 16 + lr) * 32 + lg * 8]);
    }
#pragma unroll
    for (int mi = 0; mi < 4; ++mi)
#pragma unroll
      for (int ni = 0; ni < 4; ++ni)
        acc[mi][ni] = mfma16x32(af[mi], bfr[ni], acc[mi][ni]);
  }

#pragma unroll
  for (int mi = 0; mi < 4; ++mi) {
#pragma unroll
    for (int ni = 0; ni < 4; ++ni) {
      const int col = n0 + wc + ni * 16 + lr;
#pragma unroll
      for (int r = 0; r < 4; ++r) {
        const int row = m0 + wr + mi * 16 + lg * 4 + r;
        const size_t idx = (size_t)row * Nc + col;
        float v = acc[mi][ni][r];
        if (EPI == EPI_GELU) {
          v += bias[col];
          v = 0.5f * v * (1.0f + erff(v * 0.70710678118654752f));
          outb[idx] = f2bf(v);
        } else if (EPI == EPI_ADD) {
          outf[idx] = v + add[idx];
        } else if (EPI == EPI_BIAS_ADD) {
          outf[idx] = v + bias[col] + add[idx];
        } else {
          outf[idx] = v;
        }
      }
    }
  }
}

// ---------------- 8-phase counted-vmcnt GEMM, 128x256xBK64, triple-buffer -----
// Invariant: tile t read from buf[t%3]; tile t+2 staged into buf[(t+2)%3].
// Boundary vmcnt(6) retires exactly tile t+1's 6 loads (counted, never 0 in
// steady state).  T2 st_16x32 swizzle (m201): LDS dest linear (gload_lds
// requirement), global SOURCE slot pre-swizzled, ds_read applies the same
// involution  byte ^= ((byte>>9)&1)<<5  (slot-bit-1 ^= row-bit-2; 128 B rows).

#define GP_ABYTES (128 * 64 * 2)                  // 16 KB
#define GP_BBYTES (256 * 64 * 2)                  // 32 KB
#define GP_BUFB (GP_ABYTES + GP_BBYTES)           // 48 KB/buffer, x3 = 144 KB

__device__ __forceinline__ bf16x8 lds_frag(const char* base, int row, int slot) {
  // row in [0,128|256), slot in [0,8): 16B slots of a 128 B row
  return *reinterpret_cast<const bf16x8*>(
      base + row * 128 + ((slot ^ (((row >> 2) & 1) << 1)) << 4));
}

template <int EPI>
__global__ __launch_bounds__(512, 2) void k_gemm8p(const u16* __restrict__ A,
                                                   const u16* __restrict__ BT,
                                                   int K, int Nc, int NMB,
                                                   const float* __restrict__ bias,
                                                   float* __restrict__ outf,
                                                   u16* __restrict__ outb) {
  __shared__ alignas(16) char sm[3 * GP_BUFB];
  const int nt = K >> 6;

  // XCD chunking with m-fast order: the 16 m-blocks sharing one B panel run
  // concurrently on one XCD -> B panel (0.5 MB) L2-resident, B fetched ~once.
  const int nwg = gridDim.x;
  const int bid = blockIdx.x;
  int swz = bid;
  if ((nwg & 7) == 0) swz = (bid & 7) * (nwg >> 3) + (bid >> 3);
  const int mb = swz % NMB, nb = swz / NMB;
  const int m0 = mb * 128, n0 = nb * 256;

  const int tid = threadIdx.x;
  const int w = tid >> 6, lane = tid & 63;
  const int wr = w >> 2, wc = w & 3;  // 2 x 4 wave grid
  const int lr = lane & 15, lg = lane >> 4;

  // staging: thread covers 16B chunk (srow, sslot); source slot pre-swizzled
  const int srow = tid >> 3;                       // 0..63
  const int sslot = tid & 7;                       // 16B slot
  const int gslot = sslot ^ (((srow >> 2) & 1) << 1);
  const int scol = gslot * 8;                      // k elems
  const u16* ga0 = A + (size_t)(m0 + srow) * K + scol;
  const u16* ga1 = A + (size_t)(m0 + 64 + srow) * K + scol;
  const u16* gb0 = BT + (size_t)(n0 + srow) * K + scol;
  const u16* gb1 = BT + (size_t)(n0 + 64 + srow) * K + scol;
  const u16* gb2 = BT + (size_t)(n0 + 128 + srow) * K + scol;
  const u16* gb3 = BT + (size_t)(n0 + 192 + srow) * K + scol;
  const int ldOff = srow * 128 + sslot * 16;       // linear LDS dest

#define GP_STAGE_A(b)                                   \
  {                                                     \
    gload16(ga0, sm + (b)*GP_BUFB + ldOff);             \
    gload16(ga1, sm + (b)*GP_BUFB + ldOff + 8192);      \
  }
#define GP_STAGE_B01(b)                                         \
  {                                                             \
    gload16(gb0, sm + (b)*GP_BUFB + GP_ABYTES + ldOff);         \
    gload16(gb1, sm + (b)*GP_BUFB + GP_ABYTES + ldOff + 8192);  \
  }
#define GP_STAGE_B23(b)                                          \
  {                                                              \
    gload16(gb2, sm + (b)*GP_BUFB + GP_ABYTES + ldOff + 16384);  \
    gload16(gb3, sm + (b)*GP_BUFB + GP_ABYTES + ldOff + 24576);  \
  }
#define GP_ADV() \
  { ga0 += 64; ga1 += 64; gb0 += 64; gb1 += 64; gb2 += 64; gb3 += 64; }

  // prologue: stage tiles 0,1; wait tile0 (6 of tile1's stay in flight)
  GP_STAGE_A(0) GP_STAGE_B01(0) GP_STAGE_B23(0) GP_ADV();
  GP_STAGE_A(1) GP_STAGE_B01(1) GP_STAGE_B23(1) GP_ADV();
  asm volatile("s_waitcnt vmcnt(6)" ::: "memory");
  __builtin_amdgcn_s_barrier();

  f32x4 acc[4][4] = {};
  int cur = 0, nx2 = 2;
  for (int t = 0; t < nt; ++t) {
    const char* Ab = sm + cur * GP_BUFB;
    const char* Bb = sm + cur * GP_BUFB + GP_ABYTES;
    const bool pf = (t + 2 < nt);
    bf16x8 bf[4][2];
#pragma unroll
    for (int p = 0; p < 4; ++p) {
      // ds-load this phase's A frags (mi = p); all B frags at p==0
      bf16x8 af0 = lds_frag(Ab, wr * 64 + p * 16 + lr, lg);
      bf16x8 af1 = lds_frag(Ab, wr * 64 + p * 16 + lr, 4 + lg);
      if (p == 0) {
#pragma unroll
        for (int nj = 0; nj < 4; ++nj) {
#pragma unroll
          for (int ks = 0; ks < 2; ++ks)
            bf[nj][ks] = lds_frag(Bb, wc * 64 + nj * 16 + lr, ks * 4 + lg);
        }
      }
      // stage tile t+2's share for this phase
      if (pf) {
        if (p == 0) GP_STAGE_A(nx2)
        else if (p == 1) GP_STAGE_B01(nx2)
        else if (p == 2) GP_STAGE_B23(nx2)
      }
      __builtin_amdgcn_s_barrier();
      __builtin_amdgcn_s_setprio(1);
#pragma unroll
      for (int nj = 0; nj < 4; ++nj) {
        acc[p][nj] = mfma16x32(af0, bf[nj][0], acc[p][nj]);
        acc[p][nj] = mfma16x32(af1, bf[nj][1], acc[p][nj]);
      }
      __builtin_amdgcn_s_setprio(0);
    }
    if (pf) GP_ADV();
    if (t + 1 < nt) {
      __builtin_amdgcn_sched_barrier(0);
      if (pf) asm volatile("s_waitcnt vmcnt(6)" ::: "memory");
      else    asm volatile("s_waitcnt vmcnt(0)" ::: "memory");
      __builtin_amdgcn_s_barrier();
      __builtin_amdgcn_sched_barrier(0);
    }
    cur = (cur == 2) ? 0 : cur + 1;
    nx2 = (nx2 == 2) ? 0 : nx2 + 1;
  }

#pragma unroll
  for (int mi = 0; mi < 4; ++mi) {
#pragma unroll
    for (int nj = 0; nj < 4; ++nj) {
      const int col = n0 + wc * 64 + nj * 16 + lr;
#pragma unroll
      for (int r = 0; r < 4; ++r) {
        const int row = m0 + wr * 64 + mi * 16 + lg * 4 + r;
        float v = acc[mi][nj][r];
        if (EPI == EPI_GELU) {
          v += bias[col];
          v = 0.5f * v * (1.0f + erff(v * 0.70710678118654752f));
          outb[(size_t)row * Nc + col] = f2bf(v);
        } else {
          outf[(size_t)row * Nc + col] = v;
        }
      }
    }
  }
#undef GP_STAGE_A
#undef GP_STAGE_B01
#undef GP_STAGE_B23
#undef GP_ADV
}

// ---------------------------------------------------------------- attention
__global__ __launch_bounds__(256) void k_attn(const u16* __restrict__ Qr,
                                              const u16* __restrict__ Kr,
                                              const u16* __restrict__ VT,
                                              u16* __restrict__ O) {
  __shared__ alignas(16) u16 Pl[4][16 * 32];
  const int hh = blockIdx.y;
  const int w = threadIdx.x >> 6, lane = threadIdx.x & 63;
  const int lr = lane & 15, lg = lane >> 4;
  const int q0 = blockIdx.x * 64 + w * 16;
  const u16* Qh = Qr + (size_t)hh * NSEQ * DHEAD;
  const u16* Kh = Kr + (size_t)hh * NSEQ * DHEAD;
  const u16* Vh = VT + (size_t)hh * DHEAD * NSEQ;
  u16* Pw = Pl[w];

  const bf16x8 aq0 = *reinterpret_cast<const bf16x8*>(Qh + (q0 + lr) * DHEAD + lg * 8);
  const bf16x8 aq1 = *reinterpret_cast<const bf16x8*>(Qh + (q0 + lr) * DHEAD + 32 + lg * 8);

  f32x4 o0 = {}, o1 = {}, o2 = {}, o3 = {};
  float m[4], l[4];
#pragma unroll
  for (int r = 0; r < 4; ++r) { m[r] = -1e30f; l[r] = 0.0f; }

  const int jend = q0 + 15;
  for (int j0 = 0; j0 <= jend; j0 += 32) {
    f32x4 s0 = {}, s1 = {};
    {
      bf16x8 bk;
      bk = *reinterpret_cast<const bf16x8*>(Kh + (j0 + lr) * DHEAD + lg * 8);
      s0 = mfma16x32(aq0, bk, s0);
      bk = *reinterpret_cast<const bf16x8*>(Kh + (j0 + lr) * DHEAD + 32 + lg * 8);
      s0 = mfma16x32(aq1, bk, s0);
      bk = *reinterpret_cast<const bf16x8*>(Kh + (j0 + 16 + lr) * DHEAD + lg * 8);
      s1 = mfma16x32(aq0, bk, s1);
      bk = *reinterpret_cast<const bf16x8*>(Kh + (j0 + 16 + lr) * DHEAD + 32 + lg * 8);
      s1 = mfma16x32(aq1, bk, s1);
    }
    float sv0[4], sv1[4], pm[4];
#pragma unroll
    for (int r = 0; r < 4; ++r) {
      const int irow = q0 + lg * 4 + r;
      sv0[r] = (j0 + lr > irow) ? -1e30f : s0[r] * 0.125f;
      sv1[r] = (j0 + 16 + lr > irow) ? -1e30f : s1[r] * 0.125f;
      pm[r] = fmaxf(sv0[r], sv1[r]);
    }
#pragma unroll
    for (int off = 1; off < 16; off <<= 1)
#pragma unroll
      for (int r = 0; r < 4; ++r) pm[r] = fmaxf(pm[r], __shfl_xor(pm[r], off));
    float p0[4], p1[4], rs[4];
    f32x4 fv;
#pragma unroll
    for (int r = 0; r < 4; ++r) {
      const float mn = fmaxf(m[r], pm[r]);
      fv[r] = __expf(m[r] - mn);
      m[r] = mn;
      p0[r] = __expf(sv0[r] - mn);
      p1[r] = __expf(sv1[r] - mn);
      rs[r] = p0[r] + p1[r];
    }
#pragma unroll
    for (int off = 1; off < 16; off <<= 1)
#pragma unroll
      for (int r = 0; r < 4; ++r) rs[r] += __shfl_xor(rs[r], off);
#pragma unroll
    for (int r = 0; r < 4; ++r) l[r] = l[r] * fv[r] + rs[r];
    o0 *= fv; o1 *= fv; o2 *= fv; o3 *= fv;

#pragma unroll
    for (int r = 0; r < 4; ++r) {
      Pw[(lg * 4 + r) * 32 + lr] = f2bf(p0[r]);
      Pw[(lg * 4 + r) * 32 + 16 + lr] = f2bf(p1[r]);
    }
    const bf16x8 pa = *reinterpret_cast<const bf16x8*>(Pw + lr * 32 + lg * 8);
    const u16* vb = Vh + j0 + lg * 8;
    o0 = mfma16x32(pa, *reinterpret_cast<const bf16x8*>(vb + (0 + lr) * NSEQ), o0);
    o1 = mfma16x32(pa, *reinterpret_cast<const bf16x8*>(vb + (16 + lr) * NSEQ), o1);
    o2 = mfma16x32(pa, *reinterpret_cast<const bf16x8*>(vb + (32 + lr) * NSEQ), o2);
    o3 = mfma16x32(pa, *reinterpret_cast<const bf16x8*>(vb + (48 + lr) * NSEQ), o3);
  }

#pragma unroll
  for (int r = 0; r < 4; ++r) {
    const int row = q0 + lg * 4 + r;
    const float invl = 1.0f / l[r];
    u16* orow = O + (size_t)row * DMODEL + hh * DHEAD;
    orow[0 * 16 + lr] = f2bf(o0[r] * invl);
    orow[1 * 16 + lr] = f2bf(o1[r] * invl);
    orow[2 * 16 + lr] = f2bf(o2[r] * invl);
    orow[3 * 16 + lr] = f2bf(o3[r] * invl);
  }
}

// ---------------------------------------------------------------- launch

extern "C" void kernel_launch(void* const* d_in, const int* in_sizes, int n_in,
                              void* d_out, int out_size, void* d_ws, size_t ws_size,
                              hipStream_t stream) {
  (void)in_sizes; (void)n_in;
  const int* x = (const int*)d_in[0];
  const float* emb = (const float*)d_in[1];
  const float* attn_gamma = (const float*)d_in[2];
  const float* w_qkv = (const float*)d_in[3];
  const float* w_attn_out = (const float*)d_in[4];
  const float* ff_gamma = (const float*)d_in[5];
  const float* w_ff1 = (const float*)d_in[6];
  const float* b_ff1 = (const float*)d_in[7];
  const float* w_ff2 = (const float*)d_in[8];
  const float* b_ff2 = (const float*)d_in[9];
  const float* final_gamma = (const float*)d_in[10];
  const float* w_logits = (const float*)d_in[11];
  float* out = (float*)d_out;

  const size_t EARLY_NEED = 176ull << 20;
  const size_t FINAL_NEED = 72ull << 20;
  char* earlyBase;
  char* finalBase;
  if (ws_size >= EARLY_NEED + FINAL_NEED) {
    earlyBase = (char*)d_ws;
    finalBase = (char*)d_ws + EARLY_NEED;
  } else if (ws_size >= FINAL_NEED && (size_t)out_size * 4 >= EARLY_NEED) {
    earlyBase = (char*)d_out;
    finalBase = (char*)d_ws;
  } else {
    return;
  }
  size_t eoff = 0, foff = 0;
  auto ealloc = [&](size_t b) { void* p = earlyBase + eoff; eoff += (b + 255) & ~(size_t)255; return p; };
  auto falloc = [&](size_t b) { void* p = finalBase + foff; foff += (b + 255) & ~(size_t)255; return p; };

  u16* wqkvT = (u16*)ealloc((size_t)NLAYER * 3072 * DMODEL * 2);
  u16* wattnT = (u16*)ealloc((size_t)NLAYER * DMODEL * DMODEL * 2);
  u16* wff1T = (u16*)ealloc((size_t)NLAYER * FFD * DMODEL * 2);
  u16* wff2T = (u16*)ealloc((size_t)NLAYER * DMODEL * FFD * 2);
  float* h = (float*)ealloc((size_t)NSEQ * DMODEL * 4);
  float* qkv = (float*)ealloc((size_t)NSEQ * 3072 * 4);
  u16* Qr = (u16*)ealloc((size_t)NH * NSEQ * DHEAD * 2);
  u16* Kr = (u16*)ealloc((size_t)NH * NSEQ * DHEAD * 2);
  u16* VTb = (u16*)ealloc((size_t)NH * NSEQ * DHEAD * 2);
  u16* Ob = (u16*)ealloc((size_t)NSEQ * DMODEL * 2);
  u16* ff1b = (u16*)ealloc((size_t)NSEQ * FFD * 2);
  float* ct = (float*)ealloc((size_t)NSEQ * 32 * 4);
  float* st = (float*)ealloc((size_t)NSEQ * 32 * 4);
  u16* wlogT = (u16*)falloc((size_t)VOC * DMODEL * 2);
  u16* xn = (u16*)falloc((size_t)NSEQ * DMODEL * 2);

  k_rope<<<dim3(NSEQ), dim3(32), 0, stream>>>(ct, st);
  for (int lyr = 0; lyr < NLAYER; ++lyr) {
    k_transpose<<<dim3(16, 48), 256, 0, stream>>>(
        w_qkv + (size_t)lyr * DMODEL * 3072, wqkvT + (size_t)lyr * 3072 * DMODEL, DMODEL, 3072);
    k_transpose<<<dim3(16, 16), 256, 0, stream>>>(
        w_attn_out + (size_t)lyr * DMODEL * DMODEL, wattnT + (size_t)lyr * DMODEL * DMODEL, DMODEL, DMODEL);
    k_transpose<<<dim3(16, 64), 256, 0, stream>>>(
        w_ff1 + (size_t)lyr * DMODEL * FFD, wff1T + (size_t)lyr * FFD * DMODEL, DMODEL, FFD);
    k_transpose<<<dim3(64, 16), 256, 0, stream>>>(
        w_ff2 + (size_t)lyr * FFD * DMODEL, wff2T + (size_t)lyr * DMODEL * FFD, FFD, DMODEL);
  }
  k_transpose<<<dim3(16, 500), 256, 0, stream>>>(w_logits, wlogT, DMODEL, VOC);

  k_embed<<<dim3(NSEQ), 256, 0, stream>>>(x, emb, h);

  for (int lyr = 0; lyr < NLAYER; ++lyr) {
    k_rmsnorm<<<dim3(NSEQ), 256, 0, stream>>>(h, attn_gamma + (size_t)lyr * DMODEL, xn);
    k_gemm8p<EPI_STORE><<<dim3(16 * 12), 512, 0, stream>>>(
        xn, wqkvT + (size_t)lyr * 3072 * DMODEL, DMODEL, 3072, 16, nullptr, qkv, nullptr);
    k_qkv_post<<<dim3(NSEQ, NH / 4), 256, 0, stream>>>(qkv, ct, st, Qr, Kr, VTb);
    k_attn<<<dim3(NSEQ / 64, NH), 256, 0, stream>>>(Qr, Kr, VTb, Ob);
    k_gemm<EPI_ADD><<<dim3(16, 8), 256, 0, stream>>>(
        Ob, wattnT + (size_t)lyr * DMODEL * DMODEL, DMODEL, DMODEL, nullptr, h, h, nullptr);
    k_rmsnorm<<<dim3(NSEQ), 256, 0, stream>>>(h, ff_gamma + (size_t)lyr * DMODEL, xn);
    k_gemm8p<EPI_GELU><<<dim3(16 * 16), 512, 0, stream>>>(
        xn, wff1T + (size_t)lyr * FFD * DMODEL, DMODEL, FFD, 16, b_ff1 + (size_t)lyr * FFD, nullptr, ff1b);
    k_gemm<EPI_BIAS_ADD><<<dim3(16, 8), 256, 0, stream>>>(
        ff1b, wff2T + (size_t)lyr * DMODEL * FFD, FFD, DMODEL, b_ff2 + (size_t)lyr * DMODEL, h, h, nullptr);
  }

  k_rmsnorm<<<dim3(NSEQ), 256, 0, stream>>>(h, final_gamma, xn);
  k_gemm8p<EPI_STORE><<<dim3(16 * 125), 512, 0, stream>>>(
      xn, wlogT, DMODEL, VOC, 16, nullptr, out, nullptr);
}